// Round 12
// baseline (435.276 us; speedup 1.0000x reference)
//
#include <hip/hip_runtime.h>
#include <hip/hip_fp16.h>
#include <math.h>

typedef _Float16 half_t;
typedef __attribute__((ext_vector_type(8))) _Float16 f16x8;  // MFMA A/B frag
typedef __attribute__((ext_vector_type(4))) float   f32x4;   // MFMA C/D frag
typedef __attribute__((ext_vector_type(4))) float   float4v;

#define IN_F   1536
#define HID    640
#define OUT_F  10
#define NBATCH 65536

#define SB() __builtin_amdgcn_sched_barrier(0)

// ---------- helpers ----------

__device__ __forceinline__ void gll16(const void* g, const void* l) {
    __builtin_amdgcn_global_load_lds(
        (const __attribute__((address_space(1))) unsigned*)g,
        (__attribute__((address_space(3))) unsigned*)l, 16, 0, 0);
}

// exact-GELU via A&S 7.1.26 erf poly (|eps|<=1.5e-7, noise vs f16 rounding)
__device__ __forceinline__ float gelu_fast(float z) {
    float x  = 0.70710678118654752f * z;
    float ax = fabsf(x);
    float t  = 1.0f / (1.0f + 0.3275911f * ax);
    float p  = t * (0.254829592f +
               t * (-0.284496736f +
               t * (1.421413741f +
               t * (-1.453152027f +
               t * 1.061405429f))));
    float e  = __expf(-ax * ax);
    float er = 1.0f - p * e;
    er = (x < 0.0f) ? -er : er;
    return 0.5f * z * (1.0f + er);
}

// ---------- prep: mask dtype detection + masked weight build ----------

__global__ void k_detect(const unsigned* __restrict__ m, int nDwords, int* flags) {
    int f = 0, g = 0;
    for (int i = blockIdx.x * blockDim.x + threadIdx.x; i < nDwords;
         i += gridDim.x * blockDim.x) {
        unsigned d = m[i];
        f |= (d == 0x3F800000u);
        g |= (d != 0u) & (d != 1u) & (d != 0x3F800000u);
    }
    if (f) atomicOr(&flags[0], 1);
    if (g) atomicOr(&flags[1], 1);
}

__device__ __forceinline__ bool mask_at(const void* mask, int i, int isB, int isF) {
    if (isB) return ((const unsigned char*)mask)[i] != 0;
    if (isF) return ((const float*)mask)[i] != 0.0f;
    return ((const int*)mask)[i] != 0;
}

__global__ void k_mask_all(const float* __restrict__ W1, const float* __restrict__ W2,
                           const float* __restrict__ W3,
                           const void* __restrict__ m1, const void* __restrict__ m2,
                           const void* __restrict__ m3,
                           half_t* __restrict__ W1h, half_t* __restrict__ W2h,
                           float* __restrict__ W3m, const int* __restrict__ flags) {
    const int isB = flags[1], isF = flags[0];
    const int N1 = HID * IN_F, N2 = HID * HID, N3 = OUT_F * HID;
    const int NT = N1 + N2 + N3;
    for (int i = blockIdx.x * blockDim.x + threadIdx.x; i < NT;
         i += gridDim.x * blockDim.x) {
        if (i < N1) {
            W1h[i] = mask_at(m1, i, isB, isF) ? (half_t)W1[i] : (half_t)0.0f;
        } else if (i < N1 + N2) {
            int j = i - N1;
            W2h[j] = mask_at(m2, j, isB, isF) ? (half_t)W2[j] : (half_t)0.0f;
        } else {
            int j = i - N1 - N2;
            W3m[j] = mask_at(m3, j, isB, isF) ? W3[j] : 0.0f;
        }
    }
}

// ---------- fused GEMM (+ exact GELU): A staged (3-slab ring), B direct ----------
// C[m][n] = gelu( sum_k A[m][k] * W[n][k] ), C f16 [NBATCH][HID].
// BM=256, BN=320, BK=32. 512 thr = 8 waves (2m x 4n), per-wave C = 128x80,
// acc[8][5] = 160 VGPR.
// A: gll16 -> 3-slab LDS ring (only staged operand; 4x wc-reuse needs LDS BW).
//    f32 layout [256][128B], byte = row*128 + ((slot^(row&7))<<4)  (clean).
//    f16 layout pair-packed (clean).  ONE barrier/K-step (R11-proven).
// B: DIRECT global->VGPR f16x8 frags (16 rows x 64B contiguous per op, L2-hit;
//    2x wr-redundancy -> ~40KB/step/CU through L1, under the 64 B/cyc limit).
//    Double-buffered one step ahead in regs; compiler tracks its vmcnt.
// Manual vmcnt at entry(ks) retires A(ks): outstanding after it =
//    A(ks+1) NA + B(ks) 5 -> G1 vmcnt(9), G2 vmcnt(7); tail (no A issued) 5.
// Staged bytes: G1 = 804 MB (A only), G2 = 168 MB.
template <int K, bool AF32>
__global__ __launch_bounds__(512, 2) void gemm_gelu(
    const void* __restrict__ Ain, const half_t* __restrict__ Bw,
    half_t* __restrict__ Cout) {
    constexpr int NK    = K / 32;                    // 48 or 20
    constexpr int SLAB  = AF32 ? 32768 : 16384;      // A 256 x 32 x (4|2)B
    constexpr int VMS   = AF32 ? 9 : 7;              // steady entry vmcnt
    static_assert(NK >= 4 && NK % 2 == 0, "");
    __shared__ __align__(16) char lds[3 * SLAB];     // 96KB / 48KB

    const int t = threadIdx.x, lane = t & 63, wid = t >> 6;
    const int wr = wid >> 2, wc = wid & 3;

    // XCD-bijective swizzle; nwg = 512 = 8*64, n-fastest (2 n-blocks/panel
    // adjacent on one XCD -> A-panel L2-hit on 2nd read, B L2-resident).
    const int q       = (int)gridDim.x >> 3;
    const int logical = ((int)blockIdx.x & 7) * q + ((int)blockIdx.x >> 3);
    const int mb = logical >> 1, nbk = logical & 1;
    const long mBase = (long)mb * 256;
    const int  n0    = nbk * 320;

    const int rr = lane & 15, k8 = lane >> 4;

    // ---- A fragment read bases (LDS) ----
    int aBase0 = 0, aBase1 = 0;
    {
        const int row = wr * 128 + rr;
        if constexpr (AF32) {
            aBase0 = row * 128 + (((2 * k8) ^ (row & 7)) << 4);
            aBase1 = aBase0 ^ 16;
        } else {
            const int ln = row >> 1;
            aBase0 = ln * 128 + ((((((row & 1) << 2) | k8)) ^ (ln & 7)) << 4);
        }
    }

    // ---- A staging sources (inverse-swizzled), linear gll dests ----
    const float*  srcAf = nullptr;
    const half_t* srcAh = nullptr;
    if constexpr (AF32) {
        const int row = t >> 3, kq = (t & 7) ^ ((t >> 3) & 7);
        srcAf = (const float*)Ain + (mBase + row) * (long)K + kq * 4;
    } else {
        const int line = t >> 3, orig = (t & 7) ^ (line & 7);
        const int row = 2 * line + (orig >> 2), kq = orig & 3;
        srcAh = (const half_t*)Ain + (mBase + row) * (long)K + kq * 8;
    }
    auto STAGE = [&](int k, int sb) {
        const size_t ko = (size_t)k * 32;
        if constexpr (AF32) {
#pragma unroll
            for (int r = 0; r < 4; ++r)
                gll16(srcAf + ko + (size_t)r * 64 * K,
                      &lds[sb + (t + r * 512) * 16]);
        } else {
#pragma unroll
            for (int r = 0; r < 2; ++r)
                gll16(srcAh + ko + (size_t)r * 128 * K,
                      &lds[sb + (t + r * 512) * 16]);
        }
    };

    // ---- B direct fragment base: rows n0+wc*80+nf*16+rr, 16B at k8*8 ----
    const half_t* srcBf = Bw + (size_t)(n0 + wc * 80 + rr) * K + k8 * 8;
    auto BLOAD = [&](int k, f16x8 (&bv)[5]) {
        const half_t* p = srcBf + (size_t)k * 32;
#pragma unroll
        for (int nf = 0; nf < 5; ++nf)
            bv[nf] = *(const f16x8*)(p + (size_t)nf * 16 * K);
    };

    f32x4 acc[8][5];
#pragma unroll
    for (int mf = 0; mf < 8; ++mf)
#pragma unroll
        for (int nf = 0; nf < 5; ++nf) {
            f32x4 z = {0.f, 0.f, 0.f, 0.f};
            acc[mf][nf] = z;
        }

    f16x8 bvE[5], bvO[5];

    // prologue: A(0)->slab0, A(1)->slab1, B(0)->bvE
    STAGE(0, 0); SB();
    STAGE(1, SLAB); SB();
    BLOAD(0, bvE); SB();

    auto ITER = [&](int ks, f16x8 (&bvCur)[5], f16x8 (&bvNxt)[5]) {
        // entry: retire A(ks); newest-after = A(ks+1) + B(ks) ops
        if (ks + 1 < NK)
            asm volatile("s_waitcnt vmcnt(%0)" :: "i"(VMS) : "memory");
        else
            asm volatile("s_waitcnt vmcnt(5)" ::: "memory");
        __builtin_amdgcn_s_barrier();                 // slab ks%3 ready; reads of
                                                      // slab (ks-1)%3 all done
        const int cb = (ks % 3) * SLAB;
        if (ks + 2 < NK) { STAGE(ks + 2, ((ks + 2) % 3) * SLAB); SB(); }
        if (ks + 1 < NK) { BLOAD(ks + 1, bvNxt); SB(); }

        f16x8 av[8];
        if constexpr (AF32) {
#pragma unroll
            for (int mf = 0; mf < 8; ++mf) {
                float4v alo = *(const float4v*)(&lds[cb + aBase0 + mf * 2048]);
                float4v ahi = *(const float4v*)(&lds[cb + aBase1 + mf * 2048]);
                f16x8 h;
#pragma unroll
                for (int i = 0; i < 4; ++i) {
                    h[i]     = (half_t)alo[i];
                    h[i + 4] = (half_t)ahi[i];
                }
                av[mf] = h;
            }
        } else {
#pragma unroll
            for (int mf = 0; mf < 8; ++mf)
                av[mf] = *(const f16x8*)(&lds[cb + aBase0 + mf * 1024]);
        }
#pragma unroll
        for (int mf = 0; mf < 8; ++mf)
#pragma unroll
            for (int nf = 0; nf < 5; ++nf)
                acc[mf][nf] = __builtin_amdgcn_mfma_f32_16x16x32_f16(
                    av[mf], bvCur[nf], acc[mf][nf], 0, 0, 0);
    };

    for (int ks = 0; ks < NK; ks += 2) {
        ITER(ks,     bvE, bvO);
        ITER(ks + 1, bvO, bvE);
    }

    // epilogue: C/D frag col=lane&15, row=(lane>>4)*4+j (verified mapping)
    const int crow0 = (lane >> 4) * 4;
    const int ccol  = lane & 15;
#pragma unroll
    for (int mf = 0; mf < 8; ++mf)
#pragma unroll
        for (int nf = 0; nf < 5; ++nf)
#pragma unroll
            for (int j = 0; j < 4; ++j) {
                const long row = mBase + wr * 128 + mf * 16 + crow0 + j;
                const int  col = n0 + wc * 80 + nf * 16 + ccol;
                Cout[row * HID + col] = (half_t)gelu_fast(acc[mf][nf][j]);
            }
}

// ---------- layer 3: out[b][o] = sum_k h2[b][k] * W3m[o][k], K=640, O=10 ----------
__global__ __launch_bounds__(256) void layer3_kernel(
    const half_t* __restrict__ h2, const float* __restrict__ W3m,
    float* __restrict__ out) {
    const int t = threadIdx.x, lane = t & 63, w = t >> 6;
    float w3r[OUT_F][10];
#pragma unroll
    for (int o = 0; o < OUT_F; ++o)
#pragma unroll
        for (int j = 0; j < 10; ++j)
            w3r[o][j] = W3m[o * HID + j * 64 + lane];

    for (long row = (long)blockIdx.x * 4 + w; row < NBATCH; row += (long)gridDim.x * 4) {
        float acc[OUT_F];
#pragma unroll
        for (int o = 0; o < OUT_F; ++o) acc[o] = 0.f;
        const half_t* hr = h2 + row * HID;
#pragma unroll
        for (int j = 0; j < 10; ++j) {
            const float h = (float)hr[j * 64 + lane];
#pragma unroll
            for (int o = 0; o < OUT_F; ++o) acc[o] += h * w3r[o][j];
        }
#pragma unroll
        for (int o = 0; o < OUT_F; ++o) {
            float v = acc[o];
#pragma unroll
            for (int off = 32; off >= 1; off >>= 1) v += __shfl_xor(v, off);
            if (lane == o) out[row * OUT_F + o] = v;
        }
    }
}

// ---------- launch ----------

extern "C" void kernel_launch(void* const* d_in, const int* in_sizes, int n_in,
                              void* d_out, int out_size, void* d_ws, size_t ws_size,
                              hipStream_t stream) {
    const float* x  = (const float*)d_in[0];
    const float* W1 = (const float*)d_in[1];
    const float* W2 = (const float*)d_in[2];
    const float* W3 = (const float*)d_in[3];
    const void*  m1 = d_in[4];
    const void*  m2 = d_in[5];
    const void*  m3 = d_in[6];
    float* out = (float*)d_out;

    char* ws = (char*)d_ws;
    int*    flags = (int*)ws;
    half_t* W1h = (half_t*)(ws + 256);                      // 640*1536*2
    half_t* W2h = (half_t*)(ws + 256 + 1966080);            // 640*640*2
    float*  W3m = (float*)(ws + 256 + 1966080 + 819200);    // 25600
    half_t* h1  = (half_t*)(ws + 256 + 1966080 + 819200 + 25600);
    half_t* h2  = (half_t*)((char*)h1 + (size_t)NBATCH * HID * 2);

    hipMemsetAsync(flags, 0, 8, stream);
    k_detect<<<64, 256, 0, stream>>>((const unsigned*)m1, 65536, flags);
    k_mask_all<<<1024, 256, 0, stream>>>(W1, W2, W3, m1, m2, m3, W1h, W2h, W3m, flags);

    gemm_gelu<IN_F, true><<<512, 512, 0, stream>>>((const void*)x, W1h, h1);
    gemm_gelu<HID, false><<<512, 512, 0, stream>>>((const void*)h1, W2h, h2);
    layer3_kernel<<<2048, 256, 0, stream>>>(h2, W3m, out);
}

// Round 13
// 326.682 us; speedup vs baseline: 1.3324x; 1.3324x over previous
//
#include <hip/hip_runtime.h>
#include <hip/hip_fp16.h>
#include <math.h>

typedef _Float16 half_t;
typedef __attribute__((ext_vector_type(8))) _Float16 f16x8;  // MFMA A/B frag
typedef __attribute__((ext_vector_type(4))) float   f32x4;   // MFMA C/D frag
typedef __attribute__((ext_vector_type(4))) float   float4v;

#define IN_F   1536
#define HID    640
#define OUT_F  10
#define NBATCH 65536

#define SB() __builtin_amdgcn_sched_barrier(0)

// ---------- helpers ----------

__device__ __forceinline__ void gll16(const void* g, const void* l) {
    __builtin_amdgcn_global_load_lds(
        (const __attribute__((address_space(1))) unsigned*)g,
        (__attribute__((address_space(3))) unsigned*)l, 16, 0, 0);
}

// exact-GELU via A&S 7.1.26 erf poly (|eps|<=1.5e-7, noise vs f16 rounding)
__device__ __forceinline__ float gelu_fast(float z) {
    float x  = 0.70710678118654752f * z;
    float ax = fabsf(x);
    float t  = 1.0f / (1.0f + 0.3275911f * ax);
    float p  = t * (0.254829592f +
               t * (-0.284496736f +
               t * (1.421413741f +
               t * (-1.453152027f +
               t * 1.061405429f))));
    float e  = __expf(-ax * ax);
    float er = 1.0f - p * e;
    er = (x < 0.0f) ? -er : er;
    return 0.5f * z * (1.0f + er);
}

// ---------- prep: mask dtype detection + masked weight build ----------

__global__ void k_detect(const unsigned* __restrict__ m, int nDwords, int* flags) {
    int f = 0, g = 0;
    for (int i = blockIdx.x * blockDim.x + threadIdx.x; i < nDwords;
         i += gridDim.x * blockDim.x) {
        unsigned d = m[i];
        f |= (d == 0x3F800000u);
        g |= (d != 0u) & (d != 1u) & (d != 0x3F800000u);
    }
    if (f) atomicOr(&flags[0], 1);
    if (g) atomicOr(&flags[1], 1);
}

__device__ __forceinline__ bool mask_at(const void* mask, int i, int isB, int isF) {
    if (isB) return ((const unsigned char*)mask)[i] != 0;
    if (isF) return ((const float*)mask)[i] != 0.0f;
    return ((const int*)mask)[i] != 0;
}

__global__ void k_mask_all(const float* __restrict__ W1, const float* __restrict__ W2,
                           const float* __restrict__ W3,
                           const void* __restrict__ m1, const void* __restrict__ m2,
                           const void* __restrict__ m3,
                           half_t* __restrict__ W1h, half_t* __restrict__ W2h,
                           float* __restrict__ W3m, const int* __restrict__ flags) {
    const int isB = flags[1], isF = flags[0];
    const int N1 = HID * IN_F, N2 = HID * HID, N3 = OUT_F * HID;
    const int NT = N1 + N2 + N3;
    for (int i = blockIdx.x * blockDim.x + threadIdx.x; i < NT;
         i += gridDim.x * blockDim.x) {
        if (i < N1) {
            W1h[i] = mask_at(m1, i, isB, isF) ? (half_t)W1[i] : (half_t)0.0f;
        } else if (i < N1 + N2) {
            int j = i - N1;
            W2h[j] = mask_at(m2, j, isB, isF) ? (half_t)W2[j] : (half_t)0.0f;
        } else {
            int j = i - N1 - N2;
            W3m[j] = mask_at(m3, j, isB, isF) ? W3[j] : 0.0f;
        }
    }
}

// ---------- fused GEMM (+ exact GELU), 3-slab single-barrier ring ----------
// C[m][n] = gelu( sum_k A[m][k] * W[n][k] ).
// BM=256, BN=320, BK=32. 512 thr = 8 waves (2m x 4n), per-wave C = 128x80,
// acc[8][5] = 160 VGPR. (R11-proven structure, unchanged.)
// FUSE=false: C written f16 to Cout [NBATCH][HID]   (layer 1 -> h1).
// FUSE=true : layer-3 fused — per wave multiply gelu-tile by W3 slice,
//   butterfly-reduce over the 16 col-lanes, store partials to
//   Pout[nbk*4+wc][NBATCH][10] (deterministic; k_final sums 8 slices).
template <int K, bool AF32, bool FUSE>
__global__ __launch_bounds__(512, 2) void gemm_gelu(
    const void* __restrict__ Ain, const half_t* __restrict__ Bw,
    half_t* __restrict__ Cout, const float* __restrict__ W3,
    float* __restrict__ Pout) {
    constexpr int NK     = K / 32;                    // 48 or 20
    constexpr int ABYTES = AF32 ? 32768 : 16384;      // 256 x 32 x (4|2)B
    constexpr int SLAB   = ABYTES + 20480;            // + B 320 x 32 x 2B
    constexpr int CL0    = AF32 ? 7 : 5;              // waves 0-3 ops/tile
    constexpr int CL1    = AF32 ? 6 : 4;              // waves 4-7 ops/tile
    static_assert(NK >= 4, "");
    __shared__ __align__(16) char lds[3 * SLAB];      // 156KB / 108KB

    const int t = threadIdx.x, lane = t & 63, wid = t >> 6;
    const int wr = wid >> 2, wc = wid & 3;

    // XCD-bijective swizzle; nwg = 512 = 8*64, n-fastest (2 n-blocks/panel).
    const int q       = (int)gridDim.x >> 3;
    const int logical = ((int)blockIdx.x & 7) * q + ((int)blockIdx.x >> 3);
    const int mb = logical >> 1, nbk = logical & 1;
    const long mBase = (long)mb * 256;
    const int  n0    = nbk * 320;

    const int rr = lane & 15, k8 = lane >> 4;

    // ---- fragment read address bases ----
    int aBase0 = 0, aBase1 = 0, bBase = 0;
    {
        const int row = wr * 128 + rr;
        if constexpr (AF32) {
            aBase0 = row * 128 + (((2 * k8) ^ (row & 7)) << 4);
            aBase1 = aBase0 ^ 16;
        } else {
            const int ln = row >> 1;
            aBase0 = ln * 128 + ((((((row & 1) << 2) | k8)) ^ (ln & 7)) << 4);
        }
        const int nrow = wc * 80 + rr, lnb = nrow >> 1;
        bBase = ABYTES + lnb * 128 +
                ((((((nrow & 1) << 2) | k8)) ^ (lnb & 7)) << 4);
    }

    // ---- staging sources (inverse-swizzled), linear gll dests ----
    const float*  srcAf = nullptr;
    const half_t* srcAh = nullptr;
    if constexpr (AF32) {
        const int row = t >> 3, kq = (t & 7) ^ ((t >> 3) & 7);
        srcAf = (const float*)Ain + (mBase + row) * (long)K + kq * 4;
    } else {
        const int line = t >> 3, orig = (t & 7) ^ (line & 7);
        const int row = 2 * line + (orig >> 2), kq = orig & 3;
        srcAh = (const half_t*)Ain + (mBase + row) * (long)K + kq * 8;
    }
    const half_t* srcB;
    {
        const int line = t >> 3, orig = (t & 7) ^ (line & 7);
        const int nrow = 2 * line + (orig >> 2), kq = orig & 3;
        srcB = Bw + (size_t)(n0 + nrow) * K + kq * 8;
    }

    auto STAGE = [&](int k, int sb) {
        const size_t ko = (size_t)k * 32;
        if constexpr (AF32) {
#pragma unroll
            for (int r = 0; r < 4; ++r)
                gll16(srcAf + ko + (size_t)r * 64 * K,
                      &lds[sb + (t + r * 512) * 16]);
        } else {
#pragma unroll
            for (int r = 0; r < 2; ++r)
                gll16(srcAh + ko + (size_t)r * 128 * K,
                      &lds[sb + (t + r * 512) * 16]);
        }
#pragma unroll
        for (int r = 0; r < 2; ++r)
            gll16(srcB + ko + (size_t)r * 128 * K,
                  &lds[sb + ABYTES + (t + r * 512) * 16]);
        if (t < 256)
            gll16(srcB + ko + (size_t)2 * 128 * K,
                  &lds[sb + ABYTES + (t + 1024) * 16]);
    };

    f32x4 acc[8][5];
#pragma unroll
    for (int mf = 0; mf < 8; ++mf)
#pragma unroll
        for (int nf = 0; nf < 5; ++nf) {
            f32x4 z = {0.f, 0.f, 0.f, 0.f};
            acc[mf][nf] = z;
        }

    STAGE(0, 0); SB();
    STAGE(1, SLAB); SB();

    for (int ks = 0; ks < NK; ++ks) {
        if (ks + 1 < NK) {
            if (wid < 4) asm volatile("s_waitcnt vmcnt(%0)" :: "i"(CL0) : "memory");
            else         asm volatile("s_waitcnt vmcnt(%0)" :: "i"(CL1) : "memory");
        } else {
            asm volatile("s_waitcnt vmcnt(0)" ::: "memory");
        }
        __builtin_amdgcn_s_barrier();                 // READY(ks); reads of ks-1 done
        const int cb = (ks % 3) * SLAB;
        if (ks + 2 < NK) { STAGE(ks + 2, ((ks + 2) % 3) * SLAB); SB(); }

        f16x8 bv[5];
#pragma unroll
        for (int nf = 0; nf < 5; ++nf)
            bv[nf] = *(const f16x8*)(&lds[cb + bBase + nf * 1024]);
        f16x8 av[8];
        if constexpr (AF32) {
#pragma unroll
            for (int mf = 0; mf < 8; ++mf) {
                float4v alo = *(const float4v*)(&lds[cb + aBase0 + mf * 2048]);
                float4v ahi = *(const float4v*)(&lds[cb + aBase1 + mf * 2048]);
                f16x8 h;
#pragma unroll
                for (int i = 0; i < 4; ++i) {
                    h[i]     = (half_t)alo[i];
                    h[i + 4] = (half_t)ahi[i];
                }
                av[mf] = h;
            }
        } else {
#pragma unroll
            for (int mf = 0; mf < 8; ++mf)
                av[mf] = *(const f16x8*)(&lds[cb + aBase0 + mf * 1024]);
        }
#pragma unroll
        for (int mf = 0; mf < 8; ++mf)
#pragma unroll
            for (int nf = 0; nf < 5; ++nf)
                acc[mf][nf] = __builtin_amdgcn_mfma_f32_16x16x32_f16(
                    av[mf], bv[nf], acc[mf][nf], 0, 0, 0);
    }

    // epilogue. C/D frag: col=lane&15, row=(lane>>4)*4+j (verified mapping)
    const int crow0 = (lane >> 4) * 4;
    const int ccol  = lane & 15;
    if constexpr (!FUSE) {
#pragma unroll
        for (int mf = 0; mf < 8; ++mf)
#pragma unroll
            for (int nf = 0; nf < 5; ++nf)
#pragma unroll
                for (int j = 0; j < 4; ++j) {
                    const long row = mBase + wr * 128 + mf * 16 + crow0 + j;
                    const int  col = n0 + wc * 80 + nf * 16 + ccol;
                    Cout[row * HID + col] = (half_t)gelu_fast(acc[mf][nf][j]);
                }
    } else {
        // fused layer 3: per (mf,j) row, p[o] = sum over this wave's 80 cols of
        // gelu(v) * W3[o][col]; butterfly over the 16 col-lanes (masks<16 stay
        // within the lane-group sharing rows); lane ccol==o stores the partial.
        float w3[OUT_F][5];
#pragma unroll
        for (int o = 0; o < OUT_F; ++o)
#pragma unroll
            for (int nf = 0; nf < 5; ++nf)
                w3[o][nf] = W3[o * HID + n0 + wc * 80 + nf * 16 + ccol];
        float* slice = Pout + (size_t)(nbk * 4 + wc) * NBATCH * OUT_F;
#pragma unroll
        for (int mf = 0; mf < 8; ++mf)
#pragma unroll
            for (int j = 0; j < 4; ++j) {
                float p[OUT_F];
#pragma unroll
                for (int o = 0; o < OUT_F; ++o) p[o] = 0.f;
#pragma unroll
                for (int nf = 0; nf < 5; ++nf) {
                    const float v = gelu_fast(acc[mf][nf][j]);
#pragma unroll
                    for (int o = 0; o < OUT_F; ++o) p[o] += v * w3[o][nf];
                }
#pragma unroll
                for (int mask = 1; mask < 16; mask <<= 1)
#pragma unroll
                    for (int o = 0; o < OUT_F; ++o)
                        p[o] += __shfl_xor(p[o], mask);
                float v = 0.f;                       // static-index select (rule 20)
#pragma unroll
                for (int o = 0; o < OUT_F; ++o) v = (ccol == o) ? p[o] : v;
                const long row = mBase + wr * 128 + mf * 16 + crow0 + j;
                if (ccol < OUT_F) slice[row * OUT_F + ccol] = v;
            }
    }
}

// ---------- final: out = sum of 8 partial slices (fixed order, deterministic) ----
__global__ void k_final(const float* __restrict__ P, float* __restrict__ out) {
    const int n = NBATCH * OUT_F;
    for (int i = blockIdx.x * blockDim.x + threadIdx.x; i < n;
         i += gridDim.x * blockDim.x) {
        float s0 = P[i]                 + P[(size_t)1 * n + i];
        float s1 = P[(size_t)2 * n + i] + P[(size_t)3 * n + i];
        float s2 = P[(size_t)4 * n + i] + P[(size_t)5 * n + i];
        float s3 = P[(size_t)6 * n + i] + P[(size_t)7 * n + i];
        out[i] = (s0 + s1) + (s2 + s3);
    }
}

// ---------- launch ----------

extern "C" void kernel_launch(void* const* d_in, const int* in_sizes, int n_in,
                              void* d_out, int out_size, void* d_ws, size_t ws_size,
                              hipStream_t stream) {
    const float* x  = (const float*)d_in[0];
    const float* W1 = (const float*)d_in[1];
    const float* W2 = (const float*)d_in[2];
    const float* W3 = (const float*)d_in[3];
    const void*  m1 = d_in[4];
    const void*  m2 = d_in[5];
    const void*  m3 = d_in[6];
    float* out = (float*)d_out;

    char* ws = (char*)d_ws;
    int*    flags = (int*)ws;
    half_t* W1h = (half_t*)(ws + 256);                      // 640*1536*2
    half_t* W2h = (half_t*)(ws + 256 + 1966080);            // 640*640*2
    float*  W3m = (float*)(ws + 256 + 1966080 + 819200);    // 25600
    half_t* h1  = (half_t*)(ws + 256 + 1966080 + 819200 + 25600);
    float*  Pp  = (float*)((char*)h1 + (size_t)NBATCH * HID * 2);  // 8*655360*4

    hipMemsetAsync(flags, 0, 8, stream);
    k_detect<<<64, 256, 0, stream>>>((const unsigned*)m1, 65536, flags);
    k_mask_all<<<1024, 256, 0, stream>>>(W1, W2, W3, m1, m2, m3, W1h, W2h, W3m, flags);

    gemm_gelu<IN_F, true, false><<<512, 512, 0, stream>>>(
        (const void*)x, W1h, h1, nullptr, nullptr);
    gemm_gelu<HID, false, true><<<512, 512, 0, stream>>>(
        (const void*)h1, W2h, nullptr, W3m, Pp);
    k_final<<<1024, 256, 0, stream>>>(Pp, out);
}